// Round 5
// baseline (33.803 us; speedup 1.0000x reference)
//
#include <hip/hip_runtime.h>

// LocalLinearLayer, single fused kernel, banded bf16 MFMA.
// out[b,o,c] = bias[o] + sum_{j=0..24} W[o, o+j] * xp[b, o+j, c]
// xp[q] = x[q] (q<12), x[q-12] (12<=q<4108), x[q-24] (q>=4108)
//
// Per block: 64 outputs (4 waves x 16), one batch. MFMA 16x16x32 bf16:
//   out[o0+m][c] = sum_{kappa<64} A[m][kappa] * B[kappa][c]
//   A[m][kappa] = W[o0+m, j=kappa-m] (0<=j<25 else 0), B[kappa][c] = xp[o0+kappa][c]
// A baked into LDS per block: a_lds[row][p] = W[blk_o+row, p-row] zero-padded.
// Tile t16=w reads cols [w*16, w*16+112) of rows [w*16, w*16+16).
// Both LDS tiles use T2 XOR swizzle (byte ^= (row&7)<<4) to break the
// rows-at-256B-stride ds_read_b128 bank conflict.

typedef __attribute__((ext_vector_type(8))) short short8;
typedef __attribute__((ext_vector_type(4))) float f32x4;

constexpr int Lseq = 4096;
constexpr int C    = 64;
constexpr int WIN  = 25;
constexpr int PAD  = 12;
constexpr int O_B  = 64;          // outputs per block
constexpr int PWIN = 112;         // taps staged per block (64 + 48 halo)
constexpr int NB   = 32;

__device__ __forceinline__ ushort f2bf(float f) {
    union { float f; uint u; } v; v.f = f;
    uint r = v.u + 0x7FFFu + ((v.u >> 16) & 1u);   // round-to-nearest-even
    return (ushort)(r >> 16);
}

__device__ __forceinline__ int tap_to_t(int q) {
    int t = (q < PAD) ? q : ((q < Lseq + PAD) ? q - PAD : q - 2 * PAD);
    return t > Lseq - 1 ? Lseq - 1 : t;   // clamped taps always meet zero weights
}

// byte offset into a [rows][128-short] LDS tile, T2 XOR swizzle
__device__ __forceinline__ int swz(int row, int col_sh) {
    int byte = (row << 8) + (col_sh << 1);
    return byte ^ ((row & 7) << 4);
}

__global__ __launch_bounds__(256) void lll_fused(const float* __restrict__ x,
                                                 const float* __restrict__ W,
                                                 const float* __restrict__ bias,
                                                 float* __restrict__ out) {
    __shared__ ushort x_lds[64 * 128];   // 16 KB: x bf16, [channel][tap]
    __shared__ ushort a_lds[64 * 128];   // 16 KB: shifted zero-padded W band

    const int bid   = blockIdx.x;
    const int tile  = bid >> 5;          // tile-major: bid, bid+32 share XCD slot
    const int b     = bid & 31;
    const int blk_o = tile * O_B;

    const float4* xb = (const float4*)(x + (size_t)b * Lseq * C);

    // ---- stage x -> x_lds[c][p], f32 -> bf16, transposed ----
#pragma unroll
    for (int s = 0; s < 4; ++s) {
        int u = threadIdx.x + 256 * s;
        if (u < 16 * (PWIN / 2)) {            // 896 units: (c4, tap-pair)
            int c4 = u & 15, tp = u >> 4, p0 = tp * 2;
            int t0 = tap_to_t(blk_o + p0);
            int t1 = tap_to_t(blk_o + p0 + 1);
            float4 f0 = xb[(size_t)t0 * 16 + c4];
            float4 f1 = xb[(size_t)t1 * 16 + c4];
            const float a0[4] = {f0.x, f0.y, f0.z, f0.w};
            const float a1[4] = {f1.x, f1.y, f1.z, f1.w};
#pragma unroll
            for (int i = 0; i < 4; ++i) {
                uint pk = (uint)f2bf(a0[i]) | ((uint)f2bf(a1[i]) << 16);
                *(uint*)((char*)x_lds + swz(c4 * 4 + i, p0)) = pk;
            }
        }
    }

    // ---- bake W band -> a_lds[row][p] = W[blk_o+row, p-row], zero-padded ----
    {
        const int pair = threadIdx.x & 63;    // wave handles one row, 64 pairs
        const int r0   = threadIdx.x >> 6;
        const int p0   = pair * 2;
#pragma unroll
        for (int s = 0; s < 16; ++s) {
            const int row = r0 + s * 4;       // rel row == shift (blk_o aligned to 64)
            const int o   = blk_o + row;
            uint pk = 0;
#pragma unroll
            for (int i = 0; i < 2; ++i) {
                int j = p0 + i - row;         // band offset
                if (j >= 0 && j < WIN) {
                    float v = W[(size_t)o * 4121 + j];   // W[o][o+j]
                    pk |= (uint)f2bf(v) << (16 * i);
                }
            }
            *(uint*)((char*)a_lds + swz(row, p0)) = pk;
        }
    }
    __syncthreads();

    // ---- compute: one 16x64 output tile per wave ----
    const int lane = threadIdx.x & 63;
    const int w    = threadIdx.x >> 6;        // t16
    const int m    = lane & 15;
    const int quad = lane >> 4;
    const int o0   = blk_o + w * 16;

    f32x4 acc[4];
    {
        const float4 bv = *((const float4*)(bias + o0) + quad);
        const float bb[4] = {bv.x, bv.y, bv.z, bv.w};
#pragma unroll
        for (int r = 0; r < 4; ++r)
#pragma unroll
            for (int g = 0; g < 4; ++g) acc[g][r] = bb[r];
    }

#pragma unroll
    for (int ch = 0; ch < 2; ++ch) {
        const int col = w * 16 + ch * 32 + quad * 8;   // kappa window
        short8 a = *(const short8*)((const char*)a_lds + swz(w * 16 + m, col));
#pragma unroll
        for (int g = 0; g < 4; ++g) {
            short8 bf = *(const short8*)((const char*)x_lds + swz(m + 16 * g, col));
            acc[g] = __builtin_amdgcn_mfma_f32_16x16x32_bf16(a, bf, acc[g], 0, 0, 0);
        }
    }

    float* ob = out + (size_t)b * Lseq * C;
#pragma unroll
    for (int g = 0; g < 4; ++g)
#pragma unroll
        for (int r = 0; r < 4; ++r)
            ob[(size_t)(o0 + quad * 4 + r) * C + m + 16 * g] = acc[g][r];
}

extern "C" void kernel_launch(void* const* d_in, const int* in_sizes, int n_in,
                              void* d_out, int out_size, void* d_ws, size_t ws_size,
                              hipStream_t stream) {
    const float* x    = (const float*)d_in[0];
    const float* W    = (const float*)d_in[1];
    const float* bias = (const float*)d_in[2];
    float*       out  = (float*)d_out;

    lll_fused<<<NB * (Lseq / O_B), 256, 0, stream>>>(x, W, bias, out);  // 2048 blocks
}

// Round 6
// 22.746 us; speedup vs baseline: 1.4861x; 1.4861x over previous
//
#include <hip/hip_runtime.h>

// LocalLinearLayer via banded bf16 MFMA, fragment-major pre-baked weights.
// out[b,o,c] = bias[o] + sum_{j=0..24} W[o, o+j] * xp[b, o+j, c]
// xp[q] = x[q] (q<12), x[q-12] (12<=q<4108), x[q-24] (q>=4108)
//
// Per 16-output tile at o0 (gt = o0/16), MFMA 16x16x32 bf16 over kappa in [0,64):
//   out[o0+m][c] = sum_kappa A[m][kappa]*B[kappa][c]
//   A[m][kappa] = W[o0+m, j=kappa-m] (0<=j<25 else 0), B[kappa][c] = xp[o0+kappa][c]
// akg2 is FRAGMENT-major: akg2[((gt*2+c)*64+lane)*8 + e] = A[lane&15][c*32+(lane>>4)*8+e]
// -> the wave's A-load is one fully coalesced 1KB b128 instruction.

typedef __attribute__((ext_vector_type(8))) short short8;
typedef __attribute__((ext_vector_type(4))) float f32x4;

constexpr int Lseq = 4096;
constexpr int C    = 64;
constexpr int WIN  = 25;
constexpr int PAD  = 12;
constexpr int O_B  = 128;          // outputs per block (4 waves x 2 tiles x 16)
constexpr int PWIN = 176;          // taps staged (128 + 48 halo)
constexpr int PLX  = 184;          // x_lds row stride (shorts); non-pow2 -> banks spread
constexpr int NB   = 32;
constexpr int NGT  = Lseq / 16;    // 256 global 16-tiles
constexpr size_t WS_NEEDED = (size_t)NGT * 2 * 64 * 8 * sizeof(ushort);  // 512 KB

__device__ __forceinline__ ushort f2bf(float f) {
    union { float f; uint u; } v; v.f = f;
    uint r = v.u + 0x7FFFu + ((v.u >> 16) & 1u);   // round-to-nearest-even
    return (ushort)(r >> 16);
}

__device__ __forceinline__ int tap_to_t(int q) {
    int t = (q < PAD) ? q : ((q < Lseq + PAD) ? q - PAD : q - 2 * PAD);
    return t > Lseq - 1 ? Lseq - 1 : t;   // clamped taps always meet zero weights
}

// ---- bake W band into fragment-major bf16 layout (512 KB, coalesced writes) ----
__global__ __launch_bounds__(256) void bake_frag(const float* __restrict__ W,
                                                 ushort* __restrict__ akg2) {
    const int gid  = blockIdx.x * 256 + threadIdx.x;   // 128 blocks -> 32768 frags
    const int gt   = gid >> 7;
    const int cch  = (gid >> 6) & 1;
    const int lane = gid & 63;
    const int m    = lane & 15, quad = lane >> 4;
    const int o    = gt * 16 + m;
    const int kb   = cch * 32 + quad * 8;
    short8 v;
#pragma unroll
    for (int e = 0; e < 8; ++e) {
        const int j = kb + e - m;
        float f = (j >= 0 && j < WIN) ? W[(size_t)o * 4121 + j] : 0.f;  // W[o][o+j]
        v[e] = (short)f2bf(f);
    }
    *(short8*)(akg2 + (size_t)gid * 8) = v;
}

// ---- main kernel: 256 threads, 128 outputs/block, one batch ----
__global__ __launch_bounds__(256) void lll_mfma(const float* __restrict__ x,
                                                const ushort* __restrict__ akg2,
                                                const float* __restrict__ bias,
                                                float* __restrict__ out) {
    __shared__ ushort x_lds[C * PLX];              // 23.0 KB

    const int bid   = blockIdx.x;
    const int tile  = bid >> 5;                    // consecutive bids: same tile, diff batch
    const int b     = bid & 31;                    // halo neighbors at bid+-32 -> same XCD slot
    const int blk_o = tile * O_B;

    const float4* xb = (const float4*)(x + (size_t)b * Lseq * C);

    // ---- stage x -> x_lds[c][p] bf16, 8-tap units, b128 LDS writes ----
#pragma unroll
    for (int s = 0; s < 2; ++s) {
        const int u = threadIdx.x + 256 * s;
        if (u < 16 * (PWIN / 8)) {                 // 352 units: (c4, tap-oct)
            const int c4 = u & 15, oct = u >> 4, p0 = oct * 8;
            float4 f[8];
#pragma unroll
            for (int i = 0; i < 8; ++i)
                f[i] = xb[(size_t)tap_to_t(blk_o + p0 + i) * 16 + c4];
#pragma unroll
            for (int ch = 0; ch < 4; ++ch) {
                short8 pk;
#pragma unroll
                for (int i = 0; i < 8; ++i) {
                    const float v = (ch == 0) ? f[i].x : (ch == 1) ? f[i].y
                                  : (ch == 2) ? f[i].z : f[i].w;
                    pk[i] = (short)f2bf(v);
                }
                *(short8*)&x_lds[(c4 * 4 + ch) * PLX + p0] = pk;
            }
        }
    }
    __syncthreads();

    // ---- compute: 2 16x64 output tiles per wave ----
    const int lane = threadIdx.x & 63;
    const int w    = threadIdx.x >> 6;
    const int m    = lane & 15;
    const int quad = lane >> 4;

    float* ob = out + (size_t)b * Lseq * C;

#pragma unroll
    for (int it = 0; it < 2; ++it) {
        const int t16 = w * 2 + it;
        const int o0  = blk_o + t16 * 16;
        const int gt  = tile * 8 + t16;

        f32x4 acc[4];
        {
            const float4 bv = *((const float4*)(bias + o0) + quad);
            const float bb[4] = {bv.x, bv.y, bv.z, bv.w};
#pragma unroll
            for (int r = 0; r < 4; ++r)
#pragma unroll
                for (int g = 0; g < 4; ++g) acc[g][r] = bb[r];
        }

#pragma unroll
        for (int cch = 0; cch < 2; ++cch) {
            // coalesced 1KB fragment load
            short8 a = *(const short8*)(akg2 + ((size_t)(gt * 2 + cch) * 64 + lane) * 8);
            const int poff = t16 * 16 + cch * 32 + quad * 8;
#pragma unroll
            for (int g = 0; g < 4; ++g) {
                short8 bf = *(const short8*)&x_lds[(m + 16 * g) * PLX + poff];
                acc[g] = __builtin_amdgcn_mfma_f32_16x16x32_bf16(a, bf, acc[g], 0, 0, 0);
            }
        }

#pragma unroll
        for (int g = 0; g < 4; ++g)
#pragma unroll
            for (int r = 0; r < 4; ++r)
                ob[(size_t)(o0 + quad * 4 + r) * C + m + 16 * g] = acc[g][r];
    }
}

// ---- fallback f32 path (ws too small; not expected) ----
constexpr int KO = 8, OG = 16, O_TILE = KO * OG, ROWS = KO + WIN - 1;

template <bool EDGE>
__device__ __forceinline__ void compute_tile_f32(
    const float4* __restrict__ x4b, const float* __restrict__ W,
    const float* __restrict__ bias, float4* __restrict__ out4b, int o0)
{
    float4 acc[KO];
#pragma unroll
    for (int k = 0; k < KO; ++k) { float bv = bias[o0 + k]; acc[k] = make_float4(bv, bv, bv, bv); }
    int wbase[KO];
#pragma unroll
    for (int k = 0; k < KO; ++k) wbase[k] = (o0 + k) * 4121 - k;
#pragma unroll
    for (int r = 0; r < ROWS; ++r) {
        const int p = o0 + r;
        int t = EDGE ? ((p < PAD) ? p : ((p < Lseq + PAD) ? p - PAD : p - 2 * PAD)) : (p - PAD);
        const float4 xv = x4b[(size_t)t * 16];
#pragma unroll
        for (int k = 0; k < KO; ++k) {
            const int j = r - k;
            if (j >= 0 && j < WIN) {
                const float w = W[(size_t)(wbase[k] + r)];
                acc[k].x = fmaf(w, xv.x, acc[k].x); acc[k].y = fmaf(w, xv.y, acc[k].y);
                acc[k].z = fmaf(w, xv.z, acc[k].z); acc[k].w = fmaf(w, xv.w, acc[k].w);
            }
        }
    }
#pragma unroll
    for (int k = 0; k < KO; ++k) out4b[(size_t)(o0 + k) * 16] = acc[k];
}

__global__ __launch_bounds__(256) void lll_f32(
    const float* __restrict__ x, const float* __restrict__ W,
    const float* __restrict__ bias, float* __restrict__ out)
{
    const int tid = threadIdx.x;
    const int tiles = Lseq / O_TILE;
    const int b = blockIdx.x / tiles, tile = blockIdx.x % tiles;
    const int o0 = tile * O_TILE + (tid >> 4) * KO;
    const int c4 = tid & 15;
    const float4* x4b = (const float4*)x + (size_t)b * Lseq * 16 + c4;
    float4* out4b = (float4*)out + (size_t)b * Lseq * 16 + c4;
    const bool interior = (o0 >= PAD) && (o0 + ROWS <= Lseq + PAD);
    if (interior) compute_tile_f32<false>(x4b, W, bias, out4b, o0);
    else          compute_tile_f32<true>(x4b, W, bias, out4b, o0);
}

extern "C" void kernel_launch(void* const* d_in, const int* in_sizes, int n_in,
                              void* d_out, int out_size, void* d_ws, size_t ws_size,
                              hipStream_t stream) {
    const float* x    = (const float*)d_in[0];
    const float* W    = (const float*)d_in[1];
    const float* bias = (const float*)d_in[2];
    float*       out  = (float*)d_out;

    if (ws_size >= WS_NEEDED) {
        ushort* akg2 = (ushort*)d_ws;
        bake_frag<<<NGT * 128 / 256, 256, 0, stream>>>(W, akg2);          // 128 blocks
        lll_mfma<<<NB * (Lseq / O_B), 256, 0, stream>>>(x, akg2, bias, out); // 1024 blocks
    } else {
        lll_f32<<<NB * (Lseq / O_TILE), 256, 0, stream>>>(x, W, bias, out);
    }
}